// Round 1
// baseline (45.408 us; speedup 1.0000x reference)
//
#include <hip/hip_runtime.h>
#include <math.h>

// UnrolledMeanShift: B=2, D=32, H=W=256, K=5x5, 3 iterations, fp32.
// patches are constant (unfold of original embeddings) -> stage tile in LDS once.

constexpr int Dch  = 32;
constexpr int HH   = 256;
constexpr int WW   = 256;
constexpr int KS   = 5;
constexpr int PADp = 2;
constexpr int BH   = 16;
constexpr int BW   = 16;
constexpr int TH   = BH + 2 * PADp;   // 20
constexpr int TWd  = BW + 2 * PADp;   // 20
constexpr int NPIX = TH * TWd;        // 400
constexpr int NCH  = Dch / 4;         // 8 chunk planes
constexpr int ITERS = 3;

__global__ __launch_bounds__(256, 2)
void meanshift_kernel(const float* __restrict__ E,
                      const float* __restrict__ lbw,
                      float* __restrict__ out)
{
    // channel-chunk planar: tile[c][pix] holds channels 4c..4c+3 of tile pixel pix.
    // Wave reads tile[c][base+dj]: consecutive lanes -> consecutive 16B slots,
    // slot = (const + 4*ty + tx) % 8 is uniform over 64 lanes -> conflict-free.
    __shared__ float4 tile[NCH][NPIX];   // 51200 B -> 2 blocks/CU

    const int b  = blockIdx.z;
    const int oh = blockIdx.y * BH - PADp;
    const int ow = blockIdx.x * BW - PADp;
    const int tx = threadIdx.x;          // 0..15
    const int ty = threadIdx.y;          // 0..15
    const int tid = ty * BW + tx;

    const float* Eb = E + (size_t)b * Dch * HH * WW;

    // ---- stage halo tile into LDS (coalesced global, b128 LDS writes) ----
    for (int job = tid; job < NCH * NPIX; job += BH * BW) {
        const int cc = job / NPIX;
        const int p  = job - cc * NPIX;
        const int tr = p / TWd;
        const int tc = p - tr * TWd;
        const int gh = oh + tr;
        const int gw = ow + tc;
        float4 v = make_float4(0.f, 0.f, 0.f, 0.f);
        if ((unsigned)gh < (unsigned)HH && (unsigned)gw < (unsigned)WW) {
            const float* p0 = Eb + (size_t)(4 * cc) * (HH * WW) + gh * WW + gw;
            v.x = p0[0];
            v.y = p0[1 * HH * WW];
            v.z = p0[2 * HH * WW];
            v.w = p0[3 * HH * WW];
        }
        tile[cc][p] = v;
    }
    __syncthreads();

    // bandwidth = softplus(log_bandwidth); inv_2bw2 = 1/(2 bw^2)
    const float bwv  = log1pf(__expf(lbw[0]));
    const float c2   = 1.0f / (2.0f * bwv * bwv);

    // init z = embeddings at own pixel
    float z[Dch];
    {
        const int myp = (ty + PADp) * TWd + (tx + PADp);
        #pragma unroll
        for (int c = 0; c < NCH; ++c) {
            const float4 v = tile[c][myp];
            z[4*c+0] = v.x; z[4*c+1] = v.y; z[4*c+2] = v.z; z[4*c+3] = v.w;
        }
    }

    #pragma unroll 1
    for (int it = 0; it < ITERS; ++it) {
        float num[Dch];
        #pragma unroll
        for (int d = 0; d < Dch; ++d) num[d] = 0.f;
        float den = 0.f;

        #pragma unroll 1
        for (int di = 0; di < KS; ++di) {
            const int rowbase = (ty + di) * TWd + tx;
            #pragma unroll
            for (int dj = 0; dj < KS; ++dj) {
                const int np_ = rowbase + dj;
                float p0[Dch];
                #pragma unroll
                for (int c = 0; c < NCH; ++c) {
                    const float4 v = tile[c][np_];
                    p0[4*c+0] = v.x; p0[4*c+1] = v.y;
                    p0[4*c+2] = v.z; p0[4*c+3] = v.w;
                }
                // 4-way split accumulator to break the FMA dep chain
                float a0 = 0.f, a1 = 0.f, a2 = 0.f, a3 = 0.f;
                #pragma unroll
                for (int d = 0; d < Dch; d += 4) {
                    const float t0 = p0[d+0] - z[d+0];
                    const float t1 = p0[d+1] - z[d+1];
                    const float t2 = p0[d+2] - z[d+2];
                    const float t3 = p0[d+3] - z[d+3];
                    a0 = fmaf(t0, t0, a0);
                    a1 = fmaf(t1, t1, a1);
                    a2 = fmaf(t2, t2, a2);
                    a3 = fmaf(t3, t3, a3);
                }
                const float dist = (a0 + a1) + (a2 + a3);
                const float w = __expf(-dist * c2);
                den += w;
                #pragma unroll
                for (int d = 0; d < Dch; ++d) num[d] = fmaf(w, p0[d], num[d]);
            }
        }

        const float inv = 1.0f / (den + 1e-6f);
        #pragma unroll
        for (int d = 0; d < Dch; ++d) z[d] = num[d] * inv;
    }

    // ---- write out: out[b,d,h,w] = z[d] ----
    float* Ob = out + (size_t)b * Dch * HH * WW;
    const int gh  = oh + PADp + ty;
    const int gw  = ow + PADp + tx;
    const int off = gh * WW + gw;
    #pragma unroll
    for (int d = 0; d < Dch; ++d) Ob[(size_t)d * (HH * WW) + off] = z[d];
}

extern "C" void kernel_launch(void* const* d_in, const int* in_sizes, int n_in,
                              void* d_out, int out_size, void* d_ws, size_t ws_size,
                              hipStream_t stream) {
    const float* E   = (const float*)d_in[0];
    const float* lbw = (const float*)d_in[1];
    float* out       = (float*)d_out;

    const int B = in_sizes[0] / (Dch * HH * WW);   // = 2
    dim3 grid(WW / BW, HH / BH, B);                // (16,16,2) = 512 blocks
    dim3 block(BW, BH, 1);                         // 256 threads
    hipLaunchKernelGGL(meanshift_kernel, grid, block, 0, stream, E, lbw, out);
}

// Round 2
// 41.546 us; speedup vs baseline: 1.0930x; 1.0930x over previous
//
#include <hip/hip_runtime.h>
#include <math.h>

// UnrolledMeanShift: B=2, D=32, H=W=256, K=5x5, 3 iterations.
// patches constant across iters -> stage 20x20 halo tile ONCE in LDS as fp16.
// dist^2 = |p|^2 - 2 p.z + |z|^2 ; |p|^2 precomputed per tile pixel;
// |z|^2 is a per-pixel constant offset (cancels in num/den, so its precision
// is irrelevant). Weight = exp2(A2*dot - sq[p] - zz), all log2e-folded.

typedef _Float16 h2 __attribute__((ext_vector_type(2)));
typedef _Float16 h8 __attribute__((ext_vector_type(8)));

constexpr int Dch  = 32;
constexpr int HH   = 256;
constexpr int WW   = 256;
constexpr int PADp = 2;
constexpr int BH   = 16;
constexpr int BW   = 16;
constexpr int TH   = BH + 2 * PADp;   // 20
constexpr int TWd  = BW + 2 * PADp;   // 20
constexpr int NPIX = TH * TWd;        // 400
constexpr int NCHK = 4;               // 4 chunks x 8 fp16 channels = 16B each
constexpr int ITERS = 3;
constexpr int HWp  = HH * WW;

#if __has_builtin(__builtin_amdgcn_fdot2)
__device__ __forceinline__ float fdot2f(h2 a, h2 b, float c) {
    return __builtin_amdgcn_fdot2(a, b, c, false);
}
#else
__device__ __forceinline__ float fdot2f(h2 a, h2 b, float c) {
    return c + (float)a[0] * (float)b[0] + (float)a[1] * (float)b[1];
}
#endif

#if __has_builtin(__builtin_amdgcn_exp2f)
#define EXP2F __builtin_amdgcn_exp2f
#else
__device__ __forceinline__ float EXP2F(float x) { return __expf(x * 0.69314718f); }
#endif

__global__ __launch_bounds__(256, 2)
void meanshift_kernel(const float* __restrict__ E,
                      const float* __restrict__ lbw,
                      float* __restrict__ out)
{
    // channel-chunk planar fp16: tile[c][pix] = channels 8c..8c+7 (16B).
    // 4*400*16 + 400*4 = 27.2 KB LDS.
    __shared__ h8    tile[NCHK][NPIX];
    __shared__ float sqv[NPIX];          // NC * |p|^2 per tile pixel

    const int b  = blockIdx.z;
    const int oh = blockIdx.y * BH - PADp;
    const int ow = blockIdx.x * BW - PADp;
    const int tx = threadIdx.x;          // 0..15
    const int ty = threadIdx.y;          // 0..15
    const int tid = ty * BW + tx;

    const float bwv = log1pf(__expf(lbw[0]));   // softplus
    const float c2  = 1.0f / (2.0f * bwv * bwv);
    const float L2E = 1.44269504f;
    const float A2  = 2.0f * c2 * L2E;          // coef on p.z
    const float NC  = c2 * L2E;                 // coef on |p|^2, |z|^2

    const float* Eb = E + (size_t)b * Dch * HWp;

    // ---- stage halo tile into LDS as fp16 ----
    for (int job = tid; job < NCHK * NPIX; job += BH * BW) {
        const int cc = job / NPIX;
        const int p  = job - cc * NPIX;
        const int tr = p / TWd;
        const int tc = p - tr * TWd;
        const int gh = oh + tr;
        const int gw = ow + tc;
        h8 v;
        if ((unsigned)gh < (unsigned)HH && (unsigned)gw < (unsigned)WW) {
            const float* p0 = Eb + (size_t)(8 * cc) * HWp + gh * WW + gw;
            #pragma unroll
            for (int k = 0; k < 8; ++k) v[k] = (_Float16)p0[k * HWp];
        } else {
            #pragma unroll
            for (int k = 0; k < 8; ++k) v[k] = (_Float16)0.f;
        }
        tile[cc][p] = v;
    }
    __syncthreads();

    // ---- precompute NC*|p|^2 per tile pixel (from the quantized values) ----
    for (int p = tid; p < NPIX; p += BH * BW) {
        float a0 = 0.f, a1 = 0.f, a2 = 0.f, a3 = 0.f;
        #pragma unroll
        for (int c = 0; c < NCHK; ++c) {
            h8 v = tile[c][p];
            const h2* q = (const h2*)&v;
            a0 = fdot2f(q[0], q[0], a0);
            a1 = fdot2f(q[1], q[1], a1);
            a2 = fdot2f(q[2], q[2], a2);
            a3 = fdot2f(q[3], q[3], a3);
        }
        sqv[p] = ((a0 + a1) + (a2 + a3)) * NC;
    }
    __syncthreads();

    // ---- init z = own pixel (quantized; consistent with patches) ----
    const int myp = (ty + PADp) * TWd + (tx + PADp);
    h2 z2[16];
    #pragma unroll
    for (int c = 0; c < NCHK; ++c) {
        h8 v = tile[c][myp];
        const h2* q = (const h2*)&v;
        z2[4*c+0] = q[0]; z2[4*c+1] = q[1];
        z2[4*c+2] = q[2]; z2[4*c+3] = q[3];
    }
    float zz = sqv[myp];   // NC*|z|^2 for iteration 0

    float zf[Dch];
    #pragma unroll 1
    for (int it = 0; it < ITERS; ++it) {
        float num[Dch];
        #pragma unroll
        for (int d = 0; d < Dch; ++d) num[d] = 0.f;
        float den = 0.f;

        #pragma unroll 1
        for (int di = 0; di < 5; ++di) {
            const int rowbase = (ty + di) * TWd + tx;
            #pragma unroll
            for (int dj = 0; dj < 5; ++dj) {
                const int np_ = rowbase + dj;
                h8 P0 = tile[0][np_];
                h8 P1 = tile[1][np_];
                h8 P2 = tile[2][np_];
                h8 P3 = tile[3][np_];
                const float sq = sqv[np_];
                const h2* q0 = (const h2*)&P0;
                const h2* q1 = (const h2*)&P1;
                const h2* q2 = (const h2*)&P2;
                const h2* q3 = (const h2*)&P3;
                float d0 = 0.f, d1 = 0.f, d2 = 0.f, d3 = 0.f;
                #pragma unroll
                for (int k = 0; k < 4; ++k) {
                    d0 = fdot2f(q0[k], z2[k],      d0);
                    d1 = fdot2f(q1[k], z2[4 + k],  d1);
                    d2 = fdot2f(q2[k], z2[8 + k],  d2);
                    d3 = fdot2f(q3[k], z2[12 + k], d3);
                }
                const float dot = (d0 + d1) + (d2 + d3);
                const float w = EXP2F(fmaf(A2, dot, -(sq + zz)));
                den += w;
                const _Float16* e0 = (const _Float16*)&P0;
                const _Float16* e1 = (const _Float16*)&P1;
                const _Float16* e2 = (const _Float16*)&P2;
                const _Float16* e3 = (const _Float16*)&P3;
                #pragma unroll
                for (int k = 0; k < 8; ++k) {
                    num[k]      = fmaf((float)e0[k], w, num[k]);
                    num[8 + k]  = fmaf((float)e1[k], w, num[8 + k]);
                    num[16 + k] = fmaf((float)e2[k], w, num[16 + k]);
                    num[24 + k] = fmaf((float)e3[k], w, num[24 + k]);
                }
            }
        }

        const float inv = 1.0f / (den + 1e-6f);
        #pragma unroll
        for (int d = 0; d < Dch; ++d) zf[d] = num[d] * inv;

        if (it < ITERS - 1) {
            // requantize z for next iteration's fdot2
            #pragma unroll
            for (int k = 0; k < 16; ++k)
                z2[k] = h2{(_Float16)zf[2*k], (_Float16)zf[2*k+1]};
            float a0 = 0.f, a1 = 0.f, a2 = 0.f, a3 = 0.f;
            #pragma unroll
            for (int k = 0; k < 4; ++k) {
                a0 = fdot2f(z2[k],      z2[k],      a0);
                a1 = fdot2f(z2[4 + k],  z2[4 + k],  a1);
                a2 = fdot2f(z2[8 + k],  z2[8 + k],  a2);
                a3 = fdot2f(z2[12 + k], z2[12 + k], a3);
            }
            zz = ((a0 + a1) + (a2 + a3)) * NC;
        }
    }

    // ---- write out: out[b,d,h,w] = zf[d] (full fp32 last-iter result) ----
    float* Ob = out + (size_t)b * Dch * HWp;
    const int off = (oh + PADp + ty) * WW + (ow + PADp + tx);
    #pragma unroll
    for (int d = 0; d < Dch; ++d) Ob[(size_t)d * HWp + off] = zf[d];
}

extern "C" void kernel_launch(void* const* d_in, const int* in_sizes, int n_in,
                              void* d_out, int out_size, void* d_ws, size_t ws_size,
                              hipStream_t stream) {
    const float* E   = (const float*)d_in[0];
    const float* lbw = (const float*)d_in[1];
    float* out       = (float*)d_out;

    const int B = in_sizes[0] / (Dch * HWp);       // = 2
    dim3 grid(WW / BW, HH / BH, B);                // (16,16,2) = 512 blocks
    dim3 block(BW, BH, 1);                         // 256 threads
    hipLaunchKernelGGL(meanshift_kernel, grid, block, 0, stream, E, lbw, out);
}